// Round 2
// baseline (523.458 us; speedup 1.0000x reference)
//
#include <hip/hip_runtime.h>

#define N_NODES 100000
#define N_EDGES 1600000
#define D_FEAT  64

// ---------------------------------------------------------------------------
// Workspace layout (all 4-byte aligned):
//   cnt     : int[N_NODES]        @ 0
//   row_ptr : int[N_NODES+1]      @ OFF_ROWPTR
//   pos     : int[N_NODES]        @ OFF_POS
//   es      : int[N_EDGES]        @ OFF_ES      (src, permuted into CSR order)
//   ew      : float[N_EDGES]      @ OFF_EW      (weight, permuted)
// ---------------------------------------------------------------------------
#define OFF_CNT    0
#define OFF_ROWPTR (OFF_CNT + N_NODES * 4)
#define OFF_POS    (OFF_ROWPTR + (N_NODES + 1) * 4)
#define OFF_ES     (OFF_POS + N_NODES * 4)
#define OFF_EW     (OFF_ES + N_EDGES * 4)
#define WS_NEEDED  (size_t)(OFF_EW + N_EDGES * 4)

__global__ void k_zero(int* __restrict__ cnt) {
    int i = blockIdx.x * blockDim.x + threadIdx.x;
    if (i < N_NODES) cnt[i] = 0;
}

__global__ void k_hist(const int* __restrict__ dst, int* __restrict__ cnt) {
    int e = blockIdx.x * blockDim.x + threadIdx.x;
    if (e < N_EDGES) atomicAdd(&cnt[dst[e]], 1);
}

// Single-block exclusive scan over N_NODES counts -> row_ptr (and pos copy).
#define SCAN_THREADS 1024
__global__ void k_scan(const int* __restrict__ cnt,
                       int* __restrict__ row_ptr,
                       int* __restrict__ pos) {
    __shared__ int sums[SCAN_THREADS];
    const int t = threadIdx.x;
    const int per = (N_NODES + SCAN_THREADS - 1) / SCAN_THREADS;  // 98
    const int lo = t * per;
    const int hi = min(lo + per, N_NODES);
    int s = 0;
    for (int i = lo; i < hi; ++i) s += cnt[i];
    sums[t] = s;
    __syncthreads();
    if (t == 0) {
        int run = 0;
        for (int i = 0; i < SCAN_THREADS; ++i) {
            int v = sums[i];
            sums[i] = run;
            run += v;
        }
    }
    __syncthreads();
    int run = sums[t];
    for (int i = lo; i < hi; ++i) {
        row_ptr[i] = run;
        pos[i] = run;
        run += cnt[i];
    }
    if (lo < N_NODES && hi == N_NODES) row_ptr[N_NODES] = run;  // == N_EDGES
}

__global__ void k_scatter(const int* __restrict__ src,
                          const int* __restrict__ dst,
                          const float* __restrict__ weight,
                          int* __restrict__ pos,
                          int* __restrict__ es,
                          float* __restrict__ ew) {
    int e = blockIdx.x * blockDim.x + threadIdx.x;
    if (e < N_EDGES) {
        int v = dst[e];
        int idx = atomicAdd(&pos[v], 1);
        es[idx] = src[e];
        ew[idx] = weight[e];
    }
}

// One 64-lane wave per node; lane d handles feature dim d.
// Cooperative 64-wide load of the edge segment, then register shuffles.
__global__ void k_gather(const float* __restrict__ feat,
                         const float* __restrict__ bias,
                         const int* __restrict__ row_ptr,
                         const int* __restrict__ es,
                         const float* __restrict__ ew,
                         float* __restrict__ out) {
    int v = blockIdx.x * 4 + (threadIdx.x >> 6);
    int lane = threadIdx.x & 63;
    if (v >= N_NODES) return;
    int g0 = row_ptr[v];
    int g1 = row_ptr[v + 1];
    float acc = 0.0f;
    for (int base = g0; base < g1; base += 64) {
        int n = min(64, g1 - base);
        int sj = 0;
        float wj = 0.0f;
        if (base + lane < g1) {
            sj = es[base + lane];   // coalesced 64-wide segment load
            wj = ew[base + lane];
        }
        for (int j = 0; j < n; ++j) {
            int s = __shfl(sj, j);
            float w = __shfl(wj, j);
            acc += w * feat[s * D_FEAT + lane];  // coalesced 256B row read
        }
    }
    out[v * D_FEAT + lane] = acc + bias[lane];
}

// ---------------- fallback (ws too small): round-1 atomic path --------------
__global__ void init_out_kernel(const float* __restrict__ bias,
                                float* __restrict__ out) {
    int i = blockIdx.x * blockDim.x + threadIdx.x;
    if (i < N_NODES * D_FEAT) out[i] = bias[i & (D_FEAT - 1)];
}

__global__ void edge_scatter_kernel(const float* __restrict__ feat,
                                    const float* __restrict__ weight,
                                    const int* __restrict__ src,
                                    const int* __restrict__ dst,
                                    float* __restrict__ out) {
    int e = blockIdx.x * 4 + (threadIdx.x >> 6);
    int lane = threadIdx.x & 63;
    if (e < N_EDGES) {
        atomicAdd(&out[dst[e] * D_FEAT + lane], weight[e] * feat[src[e] * D_FEAT + lane]);
    }
}

extern "C" void kernel_launch(void* const* d_in, const int* in_sizes, int n_in,
                              void* d_out, int out_size, void* d_ws, size_t ws_size,
                              hipStream_t stream) {
    const float* feat   = (const float*)d_in[0];
    const float* weight = (const float*)d_in[1];
    const float* bias   = (const float*)d_in[2];
    const int*   src    = (const int*)d_in[3];
    const int*   dst    = (const int*)d_in[4];
    float* out = (float*)d_out;

    if (ws_size < WS_NEEDED) {
        // Fallback: direct atomic scatter (round-1 baseline).
        int total = N_NODES * D_FEAT;
        init_out_kernel<<<(total + 255) / 256, 256, 0, stream>>>(bias, out);
        edge_scatter_kernel<<<(N_EDGES + 3) / 4, 256, 0, stream>>>(feat, weight, src, dst, out);
        return;
    }

    char* ws = (char*)d_ws;
    int*   cnt     = (int*)(ws + OFF_CNT);
    int*   row_ptr = (int*)(ws + OFF_ROWPTR);
    int*   pos     = (int*)(ws + OFF_POS);
    int*   es      = (int*)(ws + OFF_ES);
    float* ew      = (float*)(ws + OFF_EW);

    k_zero<<<(N_NODES + 255) / 256, 256, 0, stream>>>(cnt);
    k_hist<<<(N_EDGES + 255) / 256, 256, 0, stream>>>(dst, cnt);
    k_scan<<<1, SCAN_THREADS, 0, stream>>>(cnt, row_ptr, pos);
    k_scatter<<<(N_EDGES + 255) / 256, 256, 0, stream>>>(src, dst, weight, pos, es, ew);
    k_gather<<<(N_NODES + 3) / 4, 256, 0, stream>>>(feat, bias, row_ptr, es, ew, out);
}

// Round 3
// 300.319 us; speedup vs baseline: 1.7430x; 1.7430x over previous
//
#include <hip/hip_runtime.h>

#define N_NODES 100000
#define N_EDGES 1600000
#define D_FEAT  64

#define SCAN_BLK 1024
#define NB ((N_NODES + SCAN_BLK - 1) / SCAN_BLK)   // 98 blocks

// ---------------------------------------------------------------------------
// Workspace layout:
//   cnt     : int[N_NODES]      @ OFF_CNT
//   row_ptr : int[N_NODES+1]    @ OFF_ROWPTR
//   pos     : int[N_NODES]      @ OFF_POS
//   partial : int[NB]           @ OFF_PART
//   epack   : int2[N_EDGES]     @ OFF_EPACK   (.x = src, .y = weight bits)
// ---------------------------------------------------------------------------
#define OFF_CNT    0
#define OFF_ROWPTR (OFF_CNT + N_NODES * 4)
#define OFF_POS    (OFF_ROWPTR + (N_NODES + 1) * 4)
#define OFF_PART   (OFF_POS + N_NODES * 4)
#define OFF_EPACK  (((OFF_PART + NB * 4) + 7) & ~7)
#define WS_NEEDED  (size_t)(OFF_EPACK + N_EDGES * 8)

__global__ void k_zero(int* __restrict__ cnt) {
    int i = blockIdx.x * blockDim.x + threadIdx.x;
    if (i < N_NODES) cnt[i] = 0;
}

__global__ void k_hist(const int* __restrict__ dst, int* __restrict__ cnt) {
    int e = blockIdx.x * blockDim.x + threadIdx.x;
    if (e < N_EDGES) atomicAdd(&cnt[dst[e]], 1);
}

// Phase A: per-block sums of cnt -> partial[NB]
__global__ void k_scanA(const int* __restrict__ cnt, int* __restrict__ partial) {
    __shared__ int red[SCAN_BLK / 64];
    int t = threadIdx.x;
    int i = blockIdx.x * SCAN_BLK + t;
    int c = (i < N_NODES) ? cnt[i] : 0;
    for (int o = 32; o > 0; o >>= 1) c += __shfl_down(c, o);
    if ((t & 63) == 0) red[t >> 6] = c;
    __syncthreads();
    if (t < SCAN_BLK / 64) {
        int s = red[t];
        for (int o = 8; o > 0; o >>= 1) s += __shfl_down(s, o);
        if (t == 0) partial[blockIdx.x] = s;
    }
}

// Phase B: exclusive scan of NB (=98) partials in one 128-thread block.
__global__ void k_scanB(int* __restrict__ partial) {
    __shared__ int tmp[128];
    int t = threadIdx.x;
    int v = (t < NB) ? partial[t] : 0;
    tmp[t] = v;
    __syncthreads();
    for (int off = 1; off < 128; off <<= 1) {
        int x = (t >= off) ? tmp[t - off] : 0;
        __syncthreads();
        tmp[t] += x;
        __syncthreads();
    }
    if (t < NB) partial[t] = tmp[t] - v;   // exclusive
}

// Phase C: per-block Hillis-Steele scan + block offset -> row_ptr, pos
__global__ void k_scanC(const int* __restrict__ cnt, const int* __restrict__ partial,
                        int* __restrict__ row_ptr, int* __restrict__ pos) {
    __shared__ int tmp[SCAN_BLK];
    int t = threadIdx.x;
    int i = blockIdx.x * SCAN_BLK + t;
    int c = (i < N_NODES) ? cnt[i] : 0;
    tmp[t] = c;
    __syncthreads();
    for (int off = 1; off < SCAN_BLK; off <<= 1) {
        int x = (t >= off) ? tmp[t - off] : 0;
        __syncthreads();
        tmp[t] += x;
        __syncthreads();
    }
    if (i < N_NODES) {
        int r = partial[blockIdx.x] + tmp[t] - c;   // global exclusive scan
        row_ptr[i] = r;
        pos[i] = r;
    }
    if (i == 0) row_ptr[N_NODES] = N_EDGES;
}

__global__ void k_scatter(const int* __restrict__ src,
                          const int* __restrict__ dst,
                          const float* __restrict__ weight,
                          int* __restrict__ pos,
                          int2* __restrict__ ep) {
    int e = blockIdx.x * blockDim.x + threadIdx.x;
    if (e < N_EDGES) {
        int v = dst[e];
        int idx = atomicAdd(&pos[v], 1);
        ep[idx] = make_int2(src[e], __float_as_int(weight[e]));
    }
}

// One 64-lane wave per node; lane d handles feature dim d.
__global__ void k_gather(const float* __restrict__ feat,
                         const float* __restrict__ bias,
                         const int* __restrict__ row_ptr,
                         const int2* __restrict__ ep,
                         float* __restrict__ out) {
    int v = blockIdx.x * 4 + (threadIdx.x >> 6);
    int lane = threadIdx.x & 63;
    if (v >= N_NODES) return;
    int g0 = row_ptr[v];
    int g1 = row_ptr[v + 1];
    float acc = 0.0f;
    for (int base = g0; base < g1; base += 64) {
        int n = min(64, g1 - base);
        int2 p = make_int2(0, 0);
        if (base + lane < g1) p = ep[base + lane];   // coalesced 8B segment load
        for (int j = 0; j < n; ++j) {
            int   s = __shfl(p.x, j);
            float w = __int_as_float(__shfl(p.y, j));
            acc += w * feat[s * D_FEAT + lane];      // coalesced 256B row read
        }
    }
    out[v * D_FEAT + lane] = acc + bias[lane];
}

// ---------------- fallback (ws too small): round-1 atomic path --------------
__global__ void init_out_kernel(const float* __restrict__ bias,
                                float* __restrict__ out) {
    int i = blockIdx.x * blockDim.x + threadIdx.x;
    if (i < N_NODES * D_FEAT) out[i] = bias[i & (D_FEAT - 1)];
}

__global__ void edge_scatter_kernel(const float* __restrict__ feat,
                                    const float* __restrict__ weight,
                                    const int* __restrict__ src,
                                    const int* __restrict__ dst,
                                    float* __restrict__ out) {
    int e = blockIdx.x * 4 + (threadIdx.x >> 6);
    int lane = threadIdx.x & 63;
    if (e < N_EDGES) {
        atomicAdd(&out[dst[e] * D_FEAT + lane], weight[e] * feat[src[e] * D_FEAT + lane]);
    }
}

extern "C" void kernel_launch(void* const* d_in, const int* in_sizes, int n_in,
                              void* d_out, int out_size, void* d_ws, size_t ws_size,
                              hipStream_t stream) {
    const float* feat   = (const float*)d_in[0];
    const float* weight = (const float*)d_in[1];
    const float* bias   = (const float*)d_in[2];
    const int*   src    = (const int*)d_in[3];
    const int*   dst    = (const int*)d_in[4];
    float* out = (float*)d_out;

    if (ws_size < WS_NEEDED) {
        int total = N_NODES * D_FEAT;
        init_out_kernel<<<(total + 255) / 256, 256, 0, stream>>>(bias, out);
        edge_scatter_kernel<<<(N_EDGES + 3) / 4, 256, 0, stream>>>(feat, weight, src, dst, out);
        return;
    }

    char* ws = (char*)d_ws;
    int*  cnt     = (int*)(ws + OFF_CNT);
    int*  row_ptr = (int*)(ws + OFF_ROWPTR);
    int*  pos     = (int*)(ws + OFF_POS);
    int*  partial = (int*)(ws + OFF_PART);
    int2* ep      = (int2*)(ws + OFF_EPACK);

    k_zero<<<(N_NODES + 255) / 256, 256, 0, stream>>>(cnt);
    k_hist<<<(N_EDGES + 255) / 256, 256, 0, stream>>>(dst, cnt);
    k_scanA<<<NB, SCAN_BLK, 0, stream>>>(cnt, partial);
    k_scanB<<<1, 128, 0, stream>>>(partial);
    k_scanC<<<NB, SCAN_BLK, 0, stream>>>(cnt, partial, row_ptr, pos);
    k_scatter<<<(N_EDGES + 255) / 256, 256, 0, stream>>>(src, dst, weight, pos, ep);
    k_gather<<<(N_NODES + 3) / 4, 256, 0, stream>>>(feat, bias, row_ptr, ep, out);
}

// Round 4
// 273.481 us; speedup vs baseline: 1.9141x; 1.0981x over previous
//
#include <hip/hip_runtime.h>

#define N_NODES 100000
#define N_EDGES 1600000
#define D_FEAT  64

#define SCAN_BLK 1024
#define NB ((N_NODES + SCAN_BLK - 1) / SCAN_BLK)   // 98 blocks

#define NXCD 8
#define PART_NODES (N_NODES / NXCD)                // 12500 (exact)
#define TEAM_BLOCKS 64                             // blocks per XCD team
#define SCAT_BLK 256

// ---------------------------------------------------------------------------
// Workspace layout:
//   cnt     : int[N_NODES]      @ OFF_CNT
//   row_ptr : int[N_NODES+1]    @ OFF_ROWPTR
//   pos     : int[N_NODES]      @ OFF_POS
//   partial : int[NB]           @ OFF_PART
//   epack   : int2[N_EDGES]     @ OFF_EPACK   (.x = src, .y = weight bits)
// ---------------------------------------------------------------------------
#define OFF_CNT    0
#define OFF_ROWPTR (OFF_CNT + N_NODES * 4)
#define OFF_POS    (OFF_ROWPTR + (N_NODES + 1) * 4)
#define OFF_PART   (OFF_POS + N_NODES * 4)
#define OFF_EPACK  (((OFF_PART + NB * 4) + 7) & ~7)
#define WS_NEEDED  (size_t)(OFF_EPACK + N_EDGES * 8)

__global__ void k_zero(int* __restrict__ cnt) {
    int i = blockIdx.x * blockDim.x + threadIdx.x;
    if (i < N_NODES) cnt[i] = 0;
}

__global__ void k_hist(const int* __restrict__ dst, int* __restrict__ cnt) {
    int e = blockIdx.x * blockDim.x + threadIdx.x;
    if (e < N_EDGES) atomicAdd(&cnt[__builtin_nontemporal_load(dst + e)], 1);
}

// Phase A: per-block sums of cnt -> partial[NB]
__global__ void k_scanA(const int* __restrict__ cnt, int* __restrict__ partial) {
    __shared__ int red[SCAN_BLK / 64];
    int t = threadIdx.x;
    int i = blockIdx.x * SCAN_BLK + t;
    int c = (i < N_NODES) ? cnt[i] : 0;
    for (int o = 32; o > 0; o >>= 1) c += __shfl_down(c, o);
    if ((t & 63) == 0) red[t >> 6] = c;
    __syncthreads();
    if (t < SCAN_BLK / 64) {
        int s = red[t];
        for (int o = 8; o > 0; o >>= 1) s += __shfl_down(s, o);
        if (t == 0) partial[blockIdx.x] = s;
    }
}

// Phase B: exclusive scan of NB (=98) partials in one 128-thread block.
__global__ void k_scanB(int* __restrict__ partial) {
    __shared__ int tmp[128];
    int t = threadIdx.x;
    int v = (t < NB) ? partial[t] : 0;
    tmp[t] = v;
    __syncthreads();
    for (int off = 1; off < 128; off <<= 1) {
        int x = (t >= off) ? tmp[t - off] : 0;
        __syncthreads();
        tmp[t] += x;
        __syncthreads();
    }
    if (t < NB) partial[t] = tmp[t] - v;   // exclusive
}

// Phase C: per-block Hillis-Steele scan + block offset -> row_ptr, pos
__global__ void k_scanC(const int* __restrict__ cnt, const int* __restrict__ partial,
                        int* __restrict__ row_ptr, int* __restrict__ pos) {
    __shared__ int tmp[SCAN_BLK];
    int t = threadIdx.x;
    int i = blockIdx.x * SCAN_BLK + t;
    int c = (i < N_NODES) ? cnt[i] : 0;
    tmp[t] = c;
    __syncthreads();
    for (int off = 1; off < SCAN_BLK; off <<= 1) {
        int x = (t >= off) ? tmp[t - off] : 0;
        __syncthreads();
        tmp[t] += x;
        __syncthreads();
    }
    if (i < N_NODES) {
        int r = partial[blockIdx.x] + tmp[t] - c;   // global exclusive scan
        row_ptr[i] = r;
        pos[i] = r;
    }
    if (i == 0) row_ptr[N_NODES] = N_EDGES;
}

// XCD-partitioned scatter: team x (blockIdx&7, presumed XCD x under round-robin
// dispatch) handles only dst in [x*PART_NODES, (x+1)*PART_NODES). Its ep window
// (1.6 MB) accumulates in the XCD-local L2 instead of bouncing partial lines to
// HBM. NT loads keep the 8x-amplified streaming reads out of L2.
// Correctness does NOT depend on the blockIdx->XCD mapping.
__global__ void k_scatter(const int* __restrict__ src,
                          const int* __restrict__ dst,
                          const float* __restrict__ weight,
                          int* __restrict__ pos,
                          int2* __restrict__ ep) {
    const int xcd  = blockIdx.x & (NXCD - 1);
    const int rank = blockIdx.x >> 3;            // 0..TEAM_BLOCKS-1
    const int vlo = xcd * PART_NODES;
    const int vhi = vlo + PART_NODES;
    for (int base = rank * SCAT_BLK; base < N_EDGES; base += TEAM_BLOCKS * SCAT_BLK) {
        int e = base + threadIdx.x;
        if (e < N_EDGES) {
            int v = __builtin_nontemporal_load(dst + e);
            if (v >= vlo && v < vhi) {
                int   s = __builtin_nontemporal_load(src + e);
                float w = __builtin_nontemporal_load(weight + e);
                int idx = atomicAdd(&pos[v], 1);
                ep[idx] = make_int2(s, __float_as_int(w));
            }
        }
    }
}

// One 64-lane wave per node; lane d handles feature dim d.
// 8-way unroll -> 8 independent outstanding feat-row loads per wave.
__global__ void k_gather(const float* __restrict__ feat,
                         const float* __restrict__ bias,
                         const int* __restrict__ row_ptr,
                         const int2* __restrict__ ep,
                         float* __restrict__ out) {
    int v = blockIdx.x * 4 + (threadIdx.x >> 6);
    int lane = threadIdx.x & 63;
    if (v >= N_NODES) return;
    int g0 = row_ptr[v];
    int g1 = row_ptr[v + 1];
    float a0 = 0, a1 = 0, a2 = 0, a3 = 0, a4 = 0, a5 = 0, a6 = 0, a7 = 0;
    const long long* epq = (const long long*)ep;
    for (int base = g0; base < g1; base += 64) {
        int n = min(64, g1 - base);
        long long q = 0;
        if (base + lane < g1) q = __builtin_nontemporal_load(epq + base + lane);
        int   ps = (int)(q & 0xffffffffLL);
        int   pw = (int)(q >> 32);
        int j = 0;
        for (; j + 8 <= n; j += 8) {
            int s0 = __shfl(ps, j + 0); float w0 = __int_as_float(__shfl(pw, j + 0));
            int s1 = __shfl(ps, j + 1); float w1 = __int_as_float(__shfl(pw, j + 1));
            int s2 = __shfl(ps, j + 2); float w2 = __int_as_float(__shfl(pw, j + 2));
            int s3 = __shfl(ps, j + 3); float w3 = __int_as_float(__shfl(pw, j + 3));
            int s4 = __shfl(ps, j + 4); float w4 = __int_as_float(__shfl(pw, j + 4));
            int s5 = __shfl(ps, j + 5); float w5 = __int_as_float(__shfl(pw, j + 5));
            int s6 = __shfl(ps, j + 6); float w6 = __int_as_float(__shfl(pw, j + 6));
            int s7 = __shfl(ps, j + 7); float w7 = __int_as_float(__shfl(pw, j + 7));
            float f0 = feat[s0 * D_FEAT + lane];
            float f1 = feat[s1 * D_FEAT + lane];
            float f2 = feat[s2 * D_FEAT + lane];
            float f3 = feat[s3 * D_FEAT + lane];
            float f4 = feat[s4 * D_FEAT + lane];
            float f5 = feat[s5 * D_FEAT + lane];
            float f6 = feat[s6 * D_FEAT + lane];
            float f7 = feat[s7 * D_FEAT + lane];
            a0 += w0 * f0; a1 += w1 * f1; a2 += w2 * f2; a3 += w3 * f3;
            a4 += w4 * f4; a5 += w5 * f5; a6 += w6 * f6; a7 += w7 * f7;
        }
        for (; j < n; ++j) {
            int   s = __shfl(ps, j);
            float w = __int_as_float(__shfl(pw, j));
            a0 += w * feat[s * D_FEAT + lane];
        }
    }
    out[v * D_FEAT + lane] = ((a0 + a4) + (a1 + a5)) + ((a2 + a6) + (a3 + a7)) + bias[lane];
}

// ---------------- fallback (ws too small): round-1 atomic path --------------
__global__ void init_out_kernel(const float* __restrict__ bias,
                                float* __restrict__ out) {
    int i = blockIdx.x * blockDim.x + threadIdx.x;
    if (i < N_NODES * D_FEAT) out[i] = bias[i & (D_FEAT - 1)];
}

__global__ void edge_scatter_kernel(const float* __restrict__ feat,
                                    const float* __restrict__ weight,
                                    const int* __restrict__ src,
                                    const int* __restrict__ dst,
                                    float* __restrict__ out) {
    int e = blockIdx.x * 4 + (threadIdx.x >> 6);
    int lane = threadIdx.x & 63;
    if (e < N_EDGES) {
        atomicAdd(&out[dst[e] * D_FEAT + lane], weight[e] * feat[src[e] * D_FEAT + lane]);
    }
}

extern "C" void kernel_launch(void* const* d_in, const int* in_sizes, int n_in,
                              void* d_out, int out_size, void* d_ws, size_t ws_size,
                              hipStream_t stream) {
    const float* feat   = (const float*)d_in[0];
    const float* weight = (const float*)d_in[1];
    const float* bias   = (const float*)d_in[2];
    const int*   src    = (const int*)d_in[3];
    const int*   dst    = (const int*)d_in[4];
    float* out = (float*)d_out;

    if (ws_size < WS_NEEDED) {
        int total = N_NODES * D_FEAT;
        init_out_kernel<<<(total + 255) / 256, 256, 0, stream>>>(bias, out);
        edge_scatter_kernel<<<(N_EDGES + 3) / 4, 256, 0, stream>>>(feat, weight, src, dst, out);
        return;
    }

    char* ws = (char*)d_ws;
    int*  cnt     = (int*)(ws + OFF_CNT);
    int*  row_ptr = (int*)(ws + OFF_ROWPTR);
    int*  pos     = (int*)(ws + OFF_POS);
    int*  partial = (int*)(ws + OFF_PART);
    int2* ep      = (int2*)(ws + OFF_EPACK);

    k_zero<<<(N_NODES + 255) / 256, 256, 0, stream>>>(cnt);
    k_hist<<<(N_EDGES + 255) / 256, 256, 0, stream>>>(dst, cnt);
    k_scanA<<<NB, SCAN_BLK, 0, stream>>>(cnt, partial);
    k_scanB<<<1, 128, 0, stream>>>(partial);
    k_scanC<<<NB, SCAN_BLK, 0, stream>>>(cnt, partial, row_ptr, pos);
    k_scatter<<<NXCD * TEAM_BLOCKS, SCAT_BLK, 0, stream>>>(src, dst, weight, pos, ep);
    k_gather<<<(N_NODES + 3) / 4, 256, 0, stream>>>(feat, bias, row_ptr, ep, out);
}